// Round 3
// baseline (2487.410 us; speedup 1.0000x reference)
//
#include <hip/hip_runtime.h>

#define BATCH 512
#define TMAX 1024
#define DIN 4
#define H 64
#define NC 1098

__device__ __forceinline__ float sigmoidf_(float x) {
    return 1.0f / (1.0f + __expf(-x));
}
__device__ __forceinline__ float tanhf_(float x) {
    return 1.0f - 2.0f / (__expf(2.0f * x) + 1.0f);
}

// ================= Layer 0: ONE WAVE per (seq,dir), ZERO barriers ===========
// Lane j owns h-index j and computes all 4 gates (i,f,g,o) for it. Weights
// register-resident (272 floats/lane -> ~1 wave/SIMD, fine: latency-bound).
// h broadcast via same-wave LDS write->read (in-order, no barrier); c stays
// in a register. x_t is wave-uniform; next row prefetched each step.
__global__ __launch_bounds__(64, 1) void lstm_layer0_wave(
    const float* __restrict__ x, const int* __restrict__ lengths,
    const float* __restrict__ Wih_f, const float* __restrict__ Whh_f,
    const float* __restrict__ bih_f, const float* __restrict__ bhh_f,
    const float* __restrict__ Wih_b, const float* __restrict__ Whh_b,
    const float* __restrict__ bih_b, const float* __restrict__ bhh_b,
    float* __restrict__ h0 /* [B, T, 2H] */)
{
    const int unit = blockIdx.x;
    const int b = unit >> 1, dir = unit & 1;
    const int j = threadIdx.x;
    const int L = lengths[b];

    const float* Wih = dir ? Wih_b : Wih_f;
    const float* Whh = dir ? Whh_b : Whh_f;
    const float* bih = dir ? bih_b : bih_f;
    const float* bhh = dir ? bhh_b : bhh_f;

    float wI[H], wF[H], wG[H], wO[H];
    #pragma unroll
    for (int k = 0; k < H / 4; k++) {
        float4 v;
        v = ((const float4*)(Whh + (size_t)(0*H + j) * H))[k];
        wI[4*k+0]=v.x; wI[4*k+1]=v.y; wI[4*k+2]=v.z; wI[4*k+3]=v.w;
        v = ((const float4*)(Whh + (size_t)(1*H + j) * H))[k];
        wF[4*k+0]=v.x; wF[4*k+1]=v.y; wF[4*k+2]=v.z; wF[4*k+3]=v.w;
        v = ((const float4*)(Whh + (size_t)(2*H + j) * H))[k];
        wG[4*k+0]=v.x; wG[4*k+1]=v.y; wG[4*k+2]=v.z; wG[4*k+3]=v.w;
        v = ((const float4*)(Whh + (size_t)(3*H + j) * H))[k];
        wO[4*k+0]=v.x; wO[4*k+1]=v.y; wO[4*k+2]=v.z; wO[4*k+3]=v.w;
    }
    const float4 wxI = *(const float4*)(Wih + (size_t)(0*H + j) * DIN);
    const float4 wxF = *(const float4*)(Wih + (size_t)(1*H + j) * DIN);
    const float4 wxG = *(const float4*)(Wih + (size_t)(2*H + j) * DIN);
    const float4 wxO = *(const float4*)(Wih + (size_t)(3*H + j) * DIN);
    const float bI = bih[0*H + j] + bhh[0*H + j];
    const float bF = bih[1*H + j] + bhh[1*H + j];
    const float bG = bih[2*H + j] + bhh[2*H + j];
    const float bO = bih[3*H + j] + bhh[3*H + j];

    __shared__ __align__(16) float hbuf[H];
    float c = 0.0f, h = 0.0f;
    hbuf[j] = 0.0f;

    const float4* xrow = (const float4*)(x + (size_t)b * TMAX * DIN);
    float4 xt = xrow[dir ? (L - 1) : 0];

    for (int s = 0; s < L; s++) {
        const int t  = dir ? (L - 1 - s) : s;
        const int sn = (s + 1 < L) ? (s + 1) : s;
        const int tn = dir ? (L - 1 - sn) : sn;
        float4 xnext = xrow[tn];                 // prefetch (no barrier -> no drain)

        float aI = bI, aF = bF, aG = bG, aO = bO;
        aI = fmaf(wxI.x, xt.x, aI); aI = fmaf(wxI.y, xt.y, aI);
        aI = fmaf(wxI.z, xt.z, aI); aI = fmaf(wxI.w, xt.w, aI);
        aF = fmaf(wxF.x, xt.x, aF); aF = fmaf(wxF.y, xt.y, aF);
        aF = fmaf(wxF.z, xt.z, aF); aF = fmaf(wxF.w, xt.w, aF);
        aG = fmaf(wxG.x, xt.x, aG); aG = fmaf(wxG.y, xt.y, aG);
        aG = fmaf(wxG.z, xt.z, aG); aG = fmaf(wxG.w, xt.w, aG);
        aO = fmaf(wxO.x, xt.x, aO); aO = fmaf(wxO.y, xt.y, aO);
        aO = fmaf(wxO.z, xt.z, aO); aO = fmaf(wxO.w, xt.w, aO);

        const float4* h4 = (const float4*)hbuf;  // broadcast reads (free, m136)
        #pragma unroll
        for (int k = 0; k < H / 4; k++) {
            float4 hv = h4[k];
            aI = fmaf(wI[4*k+0], hv.x, aI); aI = fmaf(wI[4*k+1], hv.y, aI);
            aI = fmaf(wI[4*k+2], hv.z, aI); aI = fmaf(wI[4*k+3], hv.w, aI);
            aF = fmaf(wF[4*k+0], hv.x, aF); aF = fmaf(wF[4*k+1], hv.y, aF);
            aF = fmaf(wF[4*k+2], hv.z, aF); aF = fmaf(wF[4*k+3], hv.w, aF);
            aG = fmaf(wG[4*k+0], hv.x, aG); aG = fmaf(wG[4*k+1], hv.y, aG);
            aG = fmaf(wG[4*k+2], hv.z, aG); aG = fmaf(wG[4*k+3], hv.w, aG);
            aO = fmaf(wO[4*k+0], hv.x, aO); aO = fmaf(wO[4*k+1], hv.y, aO);
            aO = fmaf(wO[4*k+2], hv.z, aO); aO = fmaf(wO[4*k+3], hv.w, aO);
        }
        const float ig = sigmoidf_(aI), fg = sigmoidf_(aF);
        const float gg = tanhf_(aG),   og = sigmoidf_(aO);
        c = fmaf(fg, c, ig * gg);
        h = og * tanhf_(c);
        hbuf[j] = h;   // same-wave DS write: in-order vs next step's reads
        h0[((size_t)b * TMAX + t) * (2*H) + dir * H + j] = h;  // fire-and-forget
        xt = xnext;
    }
}

// ============ Layer 1 xW GEMM (chunked): G1c = h0[:,s0:s0+CH] @ Wih^T + b ===
// Output layout gate-interleaved [b, r, j, gate] so the rec wave reads one
// coalesced dwordx4 per lane per step.
__global__ __launch_bounds__(256) void xw_gemm_chunk(
    const float* __restrict__ h0, const int* __restrict__ lengths,
    const float* __restrict__ Wih, const float* __restrict__ bih,
    const float* __restrict__ bhh, float* __restrict__ G1c, int s0, int CH)
{
    const int b  = blockIdx.y;
    const int r0 = s0 + blockIdx.x * 64;
    const int L  = lengths[b];
    if (r0 >= L) return;
    const int V = min(64, L - r0);
    const int g = threadIdx.x;
    const int j = g & 63, gate = g >> 6;

    float w[2*H];
    {
        const float4* wv = (const float4*)(Wih + (size_t)g * (2*H));
        #pragma unroll
        for (int k = 0; k < (2*H) / 4; k++) {
            float4 v = wv[k];
            w[4*k+0] = v.x; w[4*k+1] = v.y; w[4*k+2] = v.z; w[4*k+3] = v.w;
        }
    }
    const float bb = bih[g] + bhh[g];

    __shared__ __align__(16) float4 xs4[64 * 32];  // 32 KB
    {
        const float4* src = (const float4*)h0 + ((size_t)b * TMAX + r0) * 32;
        for (int i = g; i < V * 32; i += 256) xs4[i] = src[i];
    }
    __syncthreads();

    for (int r = 0; r < V; r++) {
        const float4* xr = xs4 + r * 32;
        float a0 = bb, a1 = 0.0f, a2 = 0.0f, a3 = 0.0f;
        #pragma unroll
        for (int k = 0; k < 32; k++) {
            float4 v = xr[k];
            a0 = fmaf(w[4*k+0], v.x, a0);
            a1 = fmaf(w[4*k+1], v.y, a1);
            a2 = fmaf(w[4*k+2], v.z, a2);
            a3 = fmaf(w[4*k+3], v.w, a3);
        }
        G1c[((size_t)b * CH + (r0 - s0 + r)) * 256 + j * 4 + gate] = (a0 + a1) + (a2 + a3);
    }
}

// ============ Layer 1 recurrence chunk: ONE WAVE per seq, ZERO barriers =====
// Lane j owns h-index j, all 4 gates; only the 64-K Whh dot is in the serial
// loop (xW hoisted to G1c). c/h state carried across chunk launches in ws.
// Epilogue (bwd first step + logits) fused into the chunk that reaches L.
__global__ __launch_bounds__(64, 1) void lstm_rec_chunk(
    const float* __restrict__ G1c, const float* __restrict__ h0,
    const int* __restrict__ lengths, const float* __restrict__ Whh,
    const float* __restrict__ Wih_b,
    const float* __restrict__ bih_b, const float* __restrict__ bhh_b,
    const float* __restrict__ Wout, const float* __restrict__ bout,
    float* __restrict__ out, float* __restrict__ state, int s0, int CH)
{
    const int b = blockIdx.x;
    const int j = threadIdx.x;
    const int L = lengths[b];
    if (L <= s0) return;                       // finished in an earlier chunk
    const int send = min(L, s0 + CH);

    float wI[H], wF[H], wG[H], wO[H];
    #pragma unroll
    for (int k = 0; k < H / 4; k++) {
        float4 v;
        v = ((const float4*)(Whh + (size_t)(0*H + j) * H))[k];
        wI[4*k+0]=v.x; wI[4*k+1]=v.y; wI[4*k+2]=v.z; wI[4*k+3]=v.w;
        v = ((const float4*)(Whh + (size_t)(1*H + j) * H))[k];
        wF[4*k+0]=v.x; wF[4*k+1]=v.y; wF[4*k+2]=v.z; wF[4*k+3]=v.w;
        v = ((const float4*)(Whh + (size_t)(2*H + j) * H))[k];
        wG[4*k+0]=v.x; wG[4*k+1]=v.y; wG[4*k+2]=v.z; wG[4*k+3]=v.w;
        v = ((const float4*)(Whh + (size_t)(3*H + j) * H))[k];
        wO[4*k+0]=v.x; wO[4*k+1]=v.y; wO[4*k+2]=v.z; wO[4*k+3]=v.w;
    }

    float c, h;
    if (s0 == 0) { c = 0.0f; h = 0.0f; }
    else { c = state[((size_t)b * 2 + 0) * H + j]; h = state[((size_t)b * 2 + 1) * H + j]; }

    __shared__ __align__(16) float hbuf[H];
    hbuf[j] = h;

    const float4* G4 = (const float4*)G1c + (size_t)b * CH * 64;
    float4 g4 = G4[j];                          // row 0 of this chunk
    for (int s = s0; s < send; s++) {
        const int r  = s - s0;
        const int rn = (s + 1 < send) ? (r + 1) : r;
        float4 g4n = G4[(size_t)rn * 64 + j];   // prefetch next row

        float aI = g4.x, aF = g4.y, aG = g4.z, aO = g4.w;
        const float4* h4 = (const float4*)hbuf;
        #pragma unroll
        for (int k = 0; k < H / 4; k++) {
            float4 hv = h4[k];
            aI = fmaf(wI[4*k+0], hv.x, aI); aI = fmaf(wI[4*k+1], hv.y, aI);
            aI = fmaf(wI[4*k+2], hv.z, aI); aI = fmaf(wI[4*k+3], hv.w, aI);
            aF = fmaf(wF[4*k+0], hv.x, aF); aF = fmaf(wF[4*k+1], hv.y, aF);
            aF = fmaf(wF[4*k+2], hv.z, aF); aF = fmaf(wF[4*k+3], hv.w, aF);
            aG = fmaf(wG[4*k+0], hv.x, aG); aG = fmaf(wG[4*k+1], hv.y, aG);
            aG = fmaf(wG[4*k+2], hv.z, aG); aG = fmaf(wG[4*k+3], hv.w, aG);
            aO = fmaf(wO[4*k+0], hv.x, aO); aO = fmaf(wO[4*k+1], hv.y, aO);
            aO = fmaf(wO[4*k+2], hv.z, aO); aO = fmaf(wO[4*k+3], hv.w, aO);
        }
        const float ig = sigmoidf_(aI), fg = sigmoidf_(aF);
        const float gg = tanhf_(aG),   og = sigmoidf_(aO);
        c = fmaf(fg, c, ig * gg);
        h = og * tanhf_(c);
        hbuf[j] = h;
        g4 = g4n;
    }

    if (L > send) {  // not finished: persist state for next chunk launch
        state[((size_t)b * 2 + 0) * H + j] = c;
        state[((size_t)b * 2 + 1) * H + j] = h;
        return;
    }

    // ---- epilogue: y = [h1f_last, h1b_first]; logits = y @ Wout^T + bout ---
    __shared__ __align__(16) float ybuf[2*H];
    __shared__ __align__(16) float xsb[2*H];
    ybuf[j] = h;
    {
        const float* h0row = h0 + ((size_t)b * TMAX + (L - 1)) * (2*H);
        xsb[j]     = h0row[j];
        xsb[H + j] = h0row[H + j];
    }
    // bwd first step, zero state: c = sig(i)*tanh(g); f-gate unused
    float aI = bih_b[0*H + j] + bhh_b[0*H + j];
    float aG = bih_b[2*H + j] + bhh_b[2*H + j];
    float aO = bih_b[3*H + j] + bhh_b[3*H + j];
    {
        const float4* xv  = (const float4*)xsb;
        const float4* wbi = (const float4*)(Wih_b + (size_t)(0*H + j) * (2*H));
        const float4* wbg = (const float4*)(Wih_b + (size_t)(2*H + j) * (2*H));
        const float4* wbo = (const float4*)(Wih_b + (size_t)(3*H + j) * (2*H));
        #pragma unroll
        for (int k = 0; k < (2*H) / 4; k++) {
            float4 xk = xv[k];
            float4 vi = wbi[k], vg = wbg[k], vo = wbo[k];
            aI = fmaf(vi.x, xk.x, aI); aI = fmaf(vi.y, xk.y, aI);
            aI = fmaf(vi.z, xk.z, aI); aI = fmaf(vi.w, xk.w, aI);
            aG = fmaf(vg.x, xk.x, aG); aG = fmaf(vg.y, xk.y, aG);
            aG = fmaf(vg.z, xk.z, aG); aG = fmaf(vg.w, xk.w, aG);
            aO = fmaf(vo.x, xk.x, aO); aO = fmaf(vo.y, xk.y, aO);
            aO = fmaf(vo.z, xk.z, aO); aO = fmaf(vo.w, xk.w, aO);
        }
    }
    {
        const float cb = sigmoidf_(aI) * tanhf_(aG);
        ybuf[H + j] = sigmoidf_(aO) * tanhf_(cb);
    }
    const float4* yv = (const float4*)ybuf;
    for (int o = j; o < NC; o += H) {
        float a0 = bout[o], a1 = 0.0f, a2 = 0.0f, a3 = 0.0f;
        const float4* wr = (const float4*)(Wout + (size_t)o * (2*H));
        #pragma unroll
        for (int k = 0; k < (2*H) / 4; k++) {
            float4 w2 = wr[k]; float4 yy = yv[k];
            a0 = fmaf(w2.x, yy.x, a0);
            a1 = fmaf(w2.y, yy.y, a1);
            a2 = fmaf(w2.z, yy.z, a2);
            a3 = fmaf(w2.w, yy.w, a3);
        }
        out[(size_t)b * NC + o] = (a0 + a1) + (a2 + a3);
    }
}

// ================= Fallback if ws can't hold even a 128-step G1 chunk =======
__global__ __launch_bounds__(256) void lstm_layer1_fused(
    const float* __restrict__ h0, const int* __restrict__ lengths,
    const float* __restrict__ Wih_f, const float* __restrict__ Whh_f,
    const float* __restrict__ bih_f, const float* __restrict__ bhh_f,
    const float* __restrict__ Wih_b,
    const float* __restrict__ bih_b, const float* __restrict__ bhh_b,
    const float* __restrict__ Wout, const float* __restrict__ bout,
    float* __restrict__ out)
{
    const int b = blockIdx.x;
    const int g = threadIdx.x;
    const int L = lengths[b];

    float wih[2*H];
    {
        const float4* wv = (const float4*)(Wih_f + g * (2*H));
        #pragma unroll
        for (int k = 0; k < (2*H) / 4; k++) {
            float4 v = wv[k];
            wih[4*k+0] = v.x; wih[4*k+1] = v.y; wih[4*k+2] = v.z; wih[4*k+3] = v.w;
        }
    }
    float whh[H];
    {
        const float4* wv = (const float4*)(Whh_f + g * H);
        #pragma unroll
        for (int k = 0; k < H / 4; k++) {
            float4 v = wv[k];
            whh[4*k+0] = v.x; whh[4*k+1] = v.y; whh[4*k+2] = v.z; whh[4*k+3] = v.w;
        }
    }
    const float bias = bih_f[g] + bhh_f[g];

    __shared__ __align__(16) float4 xb4[64 * 32];
    __shared__ __align__(16) float h_s[H];
    __shared__ __align__(16) float c_s[H];
    __shared__ float gates[256];
    __shared__ __align__(16) float xs[2*H];
    __shared__ __align__(16) float yvec[2*H];

    if (g < H) { h_s[g] = 0.0f; c_s[g] = 0.0f; }

    for (int s = 0; s < L; s++) {
        if ((s & 63) == 0) {
            const int V = min(64, L - s);
            const float4* src = (const float4*)h0 + ((size_t)b * TMAX + s) * 32;
            for (int i = g; i < V * 32; i += 256) xb4[i] = src[i];
            __syncthreads();
        }
        const float4* xr = xb4 + (s & 63) * 32;
        float a0 = bias, a1 = 0.0f, a2 = 0.0f, a3 = 0.0f;
        #pragma unroll
        for (int k = 0; k < 32; k++) {
            float4 v = xr[k];
            a0 = fmaf(wih[4*k+0], v.x, a0);
            a1 = fmaf(wih[4*k+1], v.y, a1);
            a2 = fmaf(wih[4*k+2], v.z, a2);
            a3 = fmaf(wih[4*k+3], v.w, a3);
        }
        const float4* h4 = (const float4*)h_s;
        #pragma unroll
        for (int k = 0; k < H / 4; k++) {
            float4 hv = h4[k];
            a0 = fmaf(whh[4*k+0], hv.x, a0);
            a1 = fmaf(whh[4*k+1], hv.y, a1);
            a2 = fmaf(whh[4*k+2], hv.z, a2);
            a3 = fmaf(whh[4*k+3], hv.w, a3);
        }
        const float acc = (a0 + a1) + (a2 + a3);
        gates[g] = (g >= 128 && g < 192) ? tanhf_(acc) : sigmoidf_(acc);
        __syncthreads();
        if (g < H) {
            const float ig = gates[g], fg = gates[H + g];
            const float gg = gates[2*H + g], og = gates[3*H + g];
            const float c = fmaf(fg, c_s[g], ig * gg);
            c_s[g] = c;
            h_s[g] = og * tanhf_(c);
        }
        __syncthreads();
    }

    if (g < H) yvec[g] = h_s[g];
    if (g < 2*H) xs[g] = h0[((size_t)b * TMAX + (L - 1)) * (2*H) + g];
    __syncthreads();

    float ab0 = bih_b[g] + bhh_b[g], ab1 = 0.0f, ab2 = 0.0f, ab3 = 0.0f;
    {
        const float4* wb4 = (const float4*)(Wih_b + (size_t)g * (2*H));
        const float4* xv4 = (const float4*)xs;
        #pragma unroll
        for (int k = 0; k < (2*H) / 4; k++) {
            float4 wv = wb4[k]; float4 xv = xv4[k];
            ab0 = fmaf(wv.x, xv.x, ab0); ab1 = fmaf(wv.y, xv.y, ab1);
            ab2 = fmaf(wv.z, xv.z, ab2); ab3 = fmaf(wv.w, xv.w, ab3);
        }
    }
    const float accb = (ab0 + ab1) + (ab2 + ab3);
    gates[g] = (g >= 128 && g < 192) ? tanhf_(accb) : sigmoidf_(accb);
    __syncthreads();
    if (g < H) {
        const float ig = gates[g];
        const float gg = gates[2*H + g], og = gates[3*H + g];
        yvec[H + g] = og * tanhf_(ig * gg);
    }
    __syncthreads();

    const float4* yv = (const float4*)yvec;
    for (int o = g; o < NC; o += 256) {
        float acc2 = bout[o];
        const float4* wr = (const float4*)(Wout + (size_t)o * (2*H));
        #pragma unroll
        for (int k = 0; k < (2*H) / 4; k++) {
            float4 w2 = wr[k]; float4 yy = yv[k];
            acc2 = fmaf(w2.x, yy.x, acc2);
            acc2 = fmaf(w2.y, yy.y, acc2);
            acc2 = fmaf(w2.z, yy.z, acc2);
            acc2 = fmaf(w2.w, yy.w, acc2);
        }
        out[(size_t)b * NC + o] = acc2;
    }
}

extern "C" void kernel_launch(void* const* d_in, const int* in_sizes, int n_in,
                              void* d_out, int out_size, void* d_ws, size_t ws_size,
                              hipStream_t stream) {
    const float* x        = (const float*)d_in[0];
    const int*   lengths  = (const int*)  d_in[1];
    const float* Wih_l0f  = (const float*)d_in[2];
    const float* Whh_l0f  = (const float*)d_in[3];
    const float* bih_l0f  = (const float*)d_in[4];
    const float* bhh_l0f  = (const float*)d_in[5];
    const float* Wih_l0b  = (const float*)d_in[6];
    const float* Whh_l0b  = (const float*)d_in[7];
    const float* bih_l0b  = (const float*)d_in[8];
    const float* bhh_l0b  = (const float*)d_in[9];
    const float* Wih_l1f  = (const float*)d_in[10];
    const float* Whh_l1f  = (const float*)d_in[11];
    const float* bih_l1f  = (const float*)d_in[12];
    const float* bhh_l1f  = (const float*)d_in[13];
    const float* Wih_l1b  = (const float*)d_in[14];
    // d_in[15] = Whh_l1b: unused (backward dir only needs its first step, h=0)
    const float* bih_l1b  = (const float*)d_in[16];
    const float* bhh_l1b  = (const float*)d_in[17];
    const float* Wout     = (const float*)d_in[18];
    const float* bout     = (const float*)d_in[19];
    float* out = (float*)d_out;

    const size_t h0_b = (size_t)BATCH * TMAX * (2*H) * sizeof(float);  // 256 MB
    const size_t st_b = (size_t)BATCH * 2 * H * sizeof(float);         // 256 KB
    float* h0    = (float*)d_ws;
    float* state = (float*)((char*)d_ws + h0_b);

    int CH = 0;
    const int cands[4] = {1024, 512, 256, 128};
    for (int i = 0; i < 4; i++) {
        const size_t need = h0_b + st_b + (size_t)cands[i] * BATCH * (4*H) * sizeof(float);
        if (ws_size >= need) { CH = cands[i]; break; }
    }

    lstm_layer0_wave<<<dim3(2 * BATCH), 64, 0, stream>>>(
        x, lengths,
        Wih_l0f, Whh_l0f, bih_l0f, bhh_l0f,
        Wih_l0b, Whh_l0b, bih_l0b, bhh_l0b, h0);

    if (CH) {
        float* G1c = (float*)((char*)d_ws + h0_b + st_b);
        for (int s0 = 0; s0 < TMAX; s0 += CH) {
            xw_gemm_chunk<<<dim3(CH / 64, BATCH), 256, 0, stream>>>(
                h0, lengths, Wih_l1f, bih_l1f, bhh_l1f, G1c, s0, CH);
            lstm_rec_chunk<<<dim3(BATCH), 64, 0, stream>>>(
                G1c, h0, lengths, Whh_l1f,
                Wih_l1b, bih_l1b, bhh_l1b, Wout, bout, out, state, s0, CH);
        }
    } else {
        lstm_layer1_fused<<<dim3(BATCH), 256, 0, stream>>>(
            h0, lengths,
            Wih_l1f, Whh_l1f, bih_l1f, bhh_l1f,
            Wih_l1b, bih_l1b, bhh_l1b, Wout, bout, out);
    }
}

// Round 4
// 1906.428 us; speedup vs baseline: 1.3047x; 1.3047x over previous
//
#include <hip/hip_runtime.h>

#define BATCH 512
#define TMAX 1024
#define DIN 4
#define H 64
#define NC 1098

__device__ __forceinline__ float sigmoidf_(float x) {
    return 1.0f / (1.0f + __expf(-x));
}
__device__ __forceinline__ float tanhf_(float x) {
    return 1.0f - 2.0f / (__expf(2.0f * x) + 1.0f);
}

// ============ Layer 0: gate-split, 2 waves per (seq,dir) unit ===============
// Wave w owns gates {2w, 2w+1} (PyTorch order i,f,g,o) of h-index j = lane.
// 128 weight floats/lane -> no spill (R3's 272/lane forced scratch spills:
// arch VGPRs cap at 256 addressable). h broadcast via LDS; c in wave-0 regs.
// h rows ring-buffered in LDS, flushed every 64 steps so no global op is in
// flight at the per-step barriers (avoids vmcnt(0) drain).
__global__ __launch_bounds__(128, 1) void lstm_layer0_gs(
    const float* __restrict__ x, const int* __restrict__ lengths,
    const float* __restrict__ Wih_f, const float* __restrict__ Whh_f,
    const float* __restrict__ bih_f, const float* __restrict__ bhh_f,
    const float* __restrict__ Wih_b, const float* __restrict__ Whh_b,
    const float* __restrict__ bih_b, const float* __restrict__ bhh_b,
    float* __restrict__ h0 /* [B, T, 2H] */)
{
    const int unit = blockIdx.x;
    const int b = unit >> 1, dir = unit & 1;
    const int t = threadIdx.x;
    const int j = t & 63, w = t >> 6;
    const int L = lengths[b];

    const float* Wih = dir ? Wih_b : Wih_f;
    const float* Whh = dir ? Whh_b : Whh_f;
    const float* bih = dir ? bih_b : bih_f;
    const float* bhh = dir ? bhh_b : bhh_f;

    const int rA = (2*w) * H + j;       // first gate row this lane owns
    const int rB = (2*w + 1) * H + j;   // second

    float wA[H], wB[H];
    #pragma unroll
    for (int k = 0; k < H / 4; k++) {
        float4 v;
        v = ((const float4*)(Whh + (size_t)rA * H))[k];
        wA[4*k+0]=v.x; wA[4*k+1]=v.y; wA[4*k+2]=v.z; wA[4*k+3]=v.w;
        v = ((const float4*)(Whh + (size_t)rB * H))[k];
        wB[4*k+0]=v.x; wB[4*k+1]=v.y; wB[4*k+2]=v.z; wB[4*k+3]=v.w;
    }
    const float4 wxA = *(const float4*)(Wih + (size_t)rA * DIN);
    const float4 wxB = *(const float4*)(Wih + (size_t)rB * DIN);
    const float bA = bih[rA] + bhh[rA];
    const float bB = bih[rB] + bhh[rB];

    __shared__ __align__(16) float4 xbuf4[TMAX];   // 16 KB: whole x[b]
    __shared__ __align__(16) float hist[64 * H];   // 16 KB: h ring
    __shared__ __align__(16) float hbuf[H];
    __shared__ __align__(16) float2 go[H];

    {
        const float4* x4 = (const float4*)x + (size_t)b * TMAX;
        for (int i = t; i < L; i += 128) xbuf4[i] = x4[i];
    }
    if (w == 0) hbuf[j] = 0.0f;
    float c = 0.0f;
    __syncthreads();

    for (int s = 0; s < L; s++) {
        const int tt = dir ? (L - 1 - s) : s;
        const float4 xt = xbuf4[tt];               // wave-uniform broadcast

        float aA0 = bA, aA1 = 0.0f, aB0 = bB, aB1 = 0.0f;
        aA0 = fmaf(wxA.x, xt.x, aA0); aA1 = fmaf(wxA.y, xt.y, aA1);
        aA0 = fmaf(wxA.z, xt.z, aA0); aA1 = fmaf(wxA.w, xt.w, aA1);
        aB0 = fmaf(wxB.x, xt.x, aB0); aB1 = fmaf(wxB.y, xt.y, aB1);
        aB0 = fmaf(wxB.z, xt.z, aB0); aB1 = fmaf(wxB.w, xt.w, aB1);

        const float4* h4 = (const float4*)hbuf;    // broadcast reads
        #pragma unroll
        for (int k = 0; k < H / 4; k++) {
            float4 hv = h4[k];
            aA0 = fmaf(wA[4*k+0], hv.x, aA0); aA1 = fmaf(wA[4*k+1], hv.y, aA1);
            aA0 = fmaf(wA[4*k+2], hv.z, aA0); aA1 = fmaf(wA[4*k+3], hv.w, aA1);
            aB0 = fmaf(wB[4*k+0], hv.x, aB0); aB1 = fmaf(wB[4*k+1], hv.y, aB1);
            aB0 = fmaf(wB[4*k+2], hv.z, aB0); aB1 = fmaf(wB[4*k+3], hv.w, aB1);
        }
        const float aA = aA0 + aA1, aB = aB0 + aB1;

        float ig = 0.0f, fg = 0.0f;
        if (w == 1) {
            go[j] = make_float2(tanhf_(aA), sigmoidf_(aB));   // g, o
        } else {
            ig = sigmoidf_(aA); fg = sigmoidf_(aB);           // i, f
        }
        __syncthreads();
        if (w == 0) {
            const float2 g2 = go[j];
            c = fmaf(fg, c, ig * g2.x);
            const float h = g2.y * tanhf_(c);
            hbuf[j] = h;
            hist[(s & 63) * H + j] = h;
        }
        __syncthreads();
        if ((s & 63) == 63 || s == L - 1) {
            const int s0c = s & ~63;
            const int nrows = s - s0c + 1;
            for (int i = t; i < nrows * 16; i += 128) {
                const int r = i >> 4, c4 = i & 15;
                const int t2 = dir ? (L - 1 - (s0c + r)) : (s0c + r);
                *(float4*)(h0 + ((size_t)b * TMAX + t2) * (2*H) + dir * H + c4 * 4) =
                    *(const float4*)(hist + r * H + c4 * 4);
            }
        }
    }
}

// ============ Layer 1 xW GEMM (chunked): G1c = h0[:,s0:s0+CH] @ Wih^T + b ===
// Gate-major output row layout [r][g] (g = gate*64+j) -> fully coalesced
// writes AND conflict-free stride-1 ds_read_b32 in the rec kernel.
__global__ __launch_bounds__(256) void xw_gemm_chunk(
    const float* __restrict__ h0, const int* __restrict__ lengths,
    const float* __restrict__ Wih, const float* __restrict__ bih,
    const float* __restrict__ bhh, float* __restrict__ G1c, int s0, int CH)
{
    const int b  = blockIdx.y;
    const int r0 = s0 + blockIdx.x * 64;
    const int L  = lengths[b];
    if (r0 >= L) return;
    const int V = min(64, L - r0);
    const int g = threadIdx.x;

    float w[2*H];
    {
        const float4* wv = (const float4*)(Wih + (size_t)g * (2*H));
        #pragma unroll
        for (int k = 0; k < (2*H) / 4; k++) {
            float4 v = wv[k];
            w[4*k+0] = v.x; w[4*k+1] = v.y; w[4*k+2] = v.z; w[4*k+3] = v.w;
        }
    }
    const float bb = bih[g] + bhh[g];

    __shared__ __align__(16) float4 xs4[64 * 32];  // 32 KB
    {
        const float4* src = (const float4*)h0 + ((size_t)b * TMAX + r0) * 32;
        for (int i = g; i < V * 32; i += 256) xs4[i] = src[i];
    }
    __syncthreads();

    for (int r = 0; r < V; r++) {
        const float4* xr = xs4 + r * 32;
        float a0 = bb, a1 = 0.0f, a2 = 0.0f, a3 = 0.0f;
        #pragma unroll
        for (int k = 0; k < 32; k++) {
            float4 v = xr[k];
            a0 = fmaf(w[4*k+0], v.x, a0);
            a1 = fmaf(w[4*k+1], v.y, a1);
            a2 = fmaf(w[4*k+2], v.z, a2);
            a3 = fmaf(w[4*k+3], v.w, a3);
        }
        G1c[((size_t)b * CH + (r0 - s0 + r)) * 256 + g] = (a0 + a1) + (a2 + a3);
    }
}

// ============ Layer 1 recurrence: gate-split 2 waves, G1 LDS-staged =========
// Only the K=64 Whh dot is serial. G1 rows bulk-copied into LDS every 64
// steps (one vmcnt drain per 64 steps); per-step reads are cheap ds_read_b32.
// Epilogue (bwd first step, zero state -> Whh_l1b unused + logits) fused in
// the chunk that reaches L. c/h state persisted across chunk launches.
__global__ __launch_bounds__(128, 1) void lstm_rec_gs(
    const float* __restrict__ G1c, const float* __restrict__ h0,
    const int* __restrict__ lengths, const float* __restrict__ Whh,
    const float* __restrict__ Wih_b,
    const float* __restrict__ bih_b, const float* __restrict__ bhh_b,
    const float* __restrict__ Wout, const float* __restrict__ bout,
    float* __restrict__ out, float* __restrict__ state, int s0, int CH)
{
    const int b = blockIdx.x;
    const int t = threadIdx.x;
    const int j = t & 63, w = t >> 6;
    const int L = lengths[b];
    if (L <= s0) return;
    const int send = min(L, s0 + CH);

    const int rA = (2*w) * H + j;
    const int rB = (2*w + 1) * H + j;
    float wA[H], wB[H];
    #pragma unroll
    for (int k = 0; k < H / 4; k++) {
        float4 v;
        v = ((const float4*)(Whh + (size_t)rA * H))[k];
        wA[4*k+0]=v.x; wA[4*k+1]=v.y; wA[4*k+2]=v.z; wA[4*k+3]=v.w;
        v = ((const float4*)(Whh + (size_t)rB * H))[k];
        wB[4*k+0]=v.x; wB[4*k+1]=v.y; wB[4*k+2]=v.z; wB[4*k+3]=v.w;
    }

    __shared__ __align__(16) float gbuf[64 * 256]; // 64 KB: 64 G1 rows
    __shared__ __align__(16) float hbuf[H];
    __shared__ __align__(16) float2 go[H];

    float c = 0.0f;
    if (s0 == 0) {
        if (w == 0) hbuf[j] = 0.0f;
    } else if (w == 0) {
        c = state[(size_t)b * 128 + j];
        hbuf[j] = state[(size_t)b * 128 + 64 + j];
    }
    __syncthreads();

    const float* Gp = G1c + (size_t)b * CH * 256;
    for (int s = s0; s < send; s++) {
        const int r = s - s0;
        if ((r & 63) == 0) {
            const int nr = min(64, (send - s0) - r);
            const float4* src = (const float4*)(Gp + (size_t)r * 256);
            float4* dst = (float4*)gbuf;
            for (int i = t; i < nr * 64; i += 128) dst[i] = src[i];
            __syncthreads();
        }
        const int rr = r & 63;
        float aA0 = gbuf[rr * 256 + w * 128 + j],      aA1 = 0.0f;
        float aB0 = gbuf[rr * 256 + w * 128 + 64 + j], aB1 = 0.0f;

        const float4* h4 = (const float4*)hbuf;
        #pragma unroll
        for (int k = 0; k < H / 4; k++) {
            float4 hv = h4[k];
            aA0 = fmaf(wA[4*k+0], hv.x, aA0); aA1 = fmaf(wA[4*k+1], hv.y, aA1);
            aA0 = fmaf(wA[4*k+2], hv.z, aA0); aA1 = fmaf(wA[4*k+3], hv.w, aA1);
            aB0 = fmaf(wB[4*k+0], hv.x, aB0); aB1 = fmaf(wB[4*k+1], hv.y, aB1);
            aB0 = fmaf(wB[4*k+2], hv.z, aB0); aB1 = fmaf(wB[4*k+3], hv.w, aB1);
        }
        const float aA = aA0 + aA1, aB = aB0 + aB1;

        float ig = 0.0f, fg = 0.0f;
        if (w == 1) {
            go[j] = make_float2(tanhf_(aA), sigmoidf_(aB));
        } else {
            ig = sigmoidf_(aA); fg = sigmoidf_(aB);
        }
        __syncthreads();
        if (w == 0) {
            const float2 g2 = go[j];
            c = fmaf(fg, c, ig * g2.x);
            hbuf[j] = g2.y * tanhf_(c);
        }
        __syncthreads();
    }

    if (send < L) {
        if (w == 0) {
            state[(size_t)b * 128 + j]      = c;
            state[(size_t)b * 128 + 64 + j] = hbuf[j];
        }
        return;
    }

    // ---- epilogue: y = [h1f_last, h1b_first]; logits = y @ Wout^T + bout ---
    __shared__ __align__(16) float ybuf[2*H];
    __shared__ __align__(16) float xsb[2*H];
    __shared__ float tg[H];
    if (w == 0) ybuf[j] = hbuf[j];
    xsb[t] = h0[((size_t)b * TMAX + (L - 1)) * (2*H) + t];
    __syncthreads();

    if (w == 1) {   // gate g (tanh)
        float a0 = bih_b[2*H + j] + bhh_b[2*H + j], a1 = 0.0f;
        const float4* wr = (const float4*)(Wih_b + (size_t)(2*H + j) * (2*H));
        const float4* xv = (const float4*)xsb;
        #pragma unroll
        for (int k = 0; k < (2*H) / 4; k++) {
            float4 wv = wr[k], xk = xv[k];
            a0 = fmaf(wv.x, xk.x, a0); a1 = fmaf(wv.y, xk.y, a1);
            a0 = fmaf(wv.z, xk.z, a0); a1 = fmaf(wv.w, xk.w, a1);
        }
        tg[j] = tanhf_(a0 + a1);
    }
    float aI = 0.0f, aO = 0.0f;
    if (w == 0) {   // gates i, o (sigmoid); f unused (zero init state)
        float i0 = bih_b[j] + bhh_b[j], i1 = 0.0f;
        float o0 = bih_b[3*H + j] + bhh_b[3*H + j], o1 = 0.0f;
        const float4* wi = (const float4*)(Wih_b + (size_t)j * (2*H));
        const float4* wo = (const float4*)(Wih_b + (size_t)(3*H + j) * (2*H));
        const float4* xv = (const float4*)xsb;
        #pragma unroll
        for (int k = 0; k < (2*H) / 4; k++) {
            float4 vi = wi[k], vo = wo[k], xk = xv[k];
            i0 = fmaf(vi.x, xk.x, i0); i1 = fmaf(vi.y, xk.y, i1);
            i0 = fmaf(vi.z, xk.z, i0); i1 = fmaf(vi.w, xk.w, i1);
            o0 = fmaf(vo.x, xk.x, o0); o1 = fmaf(vo.y, xk.y, o1);
            o0 = fmaf(vo.z, xk.z, o0); o1 = fmaf(vo.w, xk.w, o1);
        }
        aI = i0 + i1; aO = o0 + o1;
    }
    __syncthreads();
    if (w == 0) {
        const float cb = sigmoidf_(aI) * tg[j];
        ybuf[H + j] = sigmoidf_(aO) * tanhf_(cb);
    }
    __syncthreads();

    const float4* yv = (const float4*)ybuf;
    for (int o = t; o < NC; o += 128) {
        float a0 = bout[o], a1 = 0.0f, a2 = 0.0f, a3 = 0.0f;
        const float4* wr = (const float4*)(Wout + (size_t)o * (2*H));
        #pragma unroll
        for (int k = 0; k < (2*H) / 4; k++) {
            float4 w2 = wr[k]; float4 yy = yv[k];
            a0 = fmaf(w2.x, yy.x, a0);
            a1 = fmaf(w2.y, yy.y, a1);
            a2 = fmaf(w2.z, yy.z, a2);
            a3 = fmaf(w2.w, yy.w, a3);
        }
        out[(size_t)b * NC + o] = (a0 + a1) + (a2 + a3);
    }
}

// ================= Fallback if ws can't hold even a 128-step G1 chunk =======
__global__ __launch_bounds__(256) void lstm_layer1_fused(
    const float* __restrict__ h0, const int* __restrict__ lengths,
    const float* __restrict__ Wih_f, const float* __restrict__ Whh_f,
    const float* __restrict__ bih_f, const float* __restrict__ bhh_f,
    const float* __restrict__ Wih_b,
    const float* __restrict__ bih_b, const float* __restrict__ bhh_b,
    const float* __restrict__ Wout, const float* __restrict__ bout,
    float* __restrict__ out)
{
    const int b = blockIdx.x;
    const int g = threadIdx.x;
    const int L = lengths[b];

    float wih[2*H];
    {
        const float4* wv = (const float4*)(Wih_f + g * (2*H));
        #pragma unroll
        for (int k = 0; k < (2*H) / 4; k++) {
            float4 v = wv[k];
            wih[4*k+0] = v.x; wih[4*k+1] = v.y; wih[4*k+2] = v.z; wih[4*k+3] = v.w;
        }
    }
    float whh[H];
    {
        const float4* wv = (const float4*)(Whh_f + g * H);
        #pragma unroll
        for (int k = 0; k < H / 4; k++) {
            float4 v = wv[k];
            whh[4*k+0] = v.x; whh[4*k+1] = v.y; whh[4*k+2] = v.z; whh[4*k+3] = v.w;
        }
    }
    const float bias = bih_f[g] + bhh_f[g];

    __shared__ __align__(16) float4 xb4[64 * 32];
    __shared__ __align__(16) float h_s[H];
    __shared__ __align__(16) float c_s[H];
    __shared__ float gates[256];
    __shared__ __align__(16) float xs[2*H];
    __shared__ __align__(16) float yvec[2*H];

    if (g < H) { h_s[g] = 0.0f; c_s[g] = 0.0f; }

    for (int s = 0; s < L; s++) {
        if ((s & 63) == 0) {
            const int V = min(64, L - s);
            const float4* src = (const float4*)h0 + ((size_t)b * TMAX + s) * 32;
            for (int i = g; i < V * 32; i += 256) xb4[i] = src[i];
            __syncthreads();
        }
        const float4* xr = xb4 + (s & 63) * 32;
        float a0 = bias, a1 = 0.0f, a2 = 0.0f, a3 = 0.0f;
        #pragma unroll
        for (int k = 0; k < 32; k++) {
            float4 v = xr[k];
            a0 = fmaf(wih[4*k+0], v.x, a0);
            a1 = fmaf(wih[4*k+1], v.y, a1);
            a2 = fmaf(wih[4*k+2], v.z, a2);
            a3 = fmaf(wih[4*k+3], v.w, a3);
        }
        const float4* h4 = (const float4*)h_s;
        #pragma unroll
        for (int k = 0; k < H / 4; k++) {
            float4 hv = h4[k];
            a0 = fmaf(whh[4*k+0], hv.x, a0);
            a1 = fmaf(whh[4*k+1], hv.y, a1);
            a2 = fmaf(whh[4*k+2], hv.z, a2);
            a3 = fmaf(whh[4*k+3], hv.w, a3);
        }
        const float acc = (a0 + a1) + (a2 + a3);
        gates[g] = (g >= 128 && g < 192) ? tanhf_(acc) : sigmoidf_(acc);
        __syncthreads();
        if (g < H) {
            const float ig = gates[g], fg = gates[H + g];
            const float gg = gates[2*H + g], og = gates[3*H + g];
            const float c = fmaf(fg, c_s[g], ig * gg);
            c_s[g] = c;
            h_s[g] = og * tanhf_(c);
        }
        __syncthreads();
    }

    if (g < H) yvec[g] = h_s[g];
    if (g < 2*H) xs[g] = h0[((size_t)b * TMAX + (L - 1)) * (2*H) + g];
    __syncthreads();

    float ab0 = bih_b[g] + bhh_b[g], ab1 = 0.0f, ab2 = 0.0f, ab3 = 0.0f;
    {
        const float4* wb4 = (const float4*)(Wih_b + (size_t)g * (2*H));
        const float4* xv4 = (const float4*)xs;
        #pragma unroll
        for (int k = 0; k < (2*H) / 4; k++) {
            float4 wv = wb4[k]; float4 xv = xv4[k];
            ab0 = fmaf(wv.x, xv.x, ab0); ab1 = fmaf(wv.y, xv.y, ab1);
            ab2 = fmaf(wv.z, xv.z, ab2); ab3 = fmaf(wv.w, xv.w, ab3);
        }
    }
    const float accb = (ab0 + ab1) + (ab2 + ab3);
    gates[g] = (g >= 128 && g < 192) ? tanhf_(accb) : sigmoidf_(accb);
    __syncthreads();
    if (g < H) {
        const float ig = gates[g];
        const float gg = gates[2*H + g], og = gates[3*H + g];
        yvec[H + g] = og * tanhf_(ig * gg);
    }
    __syncthreads();

    const float4* yv = (const float4*)yvec;
    for (int o = g; o < NC; o += 256) {
        float acc2 = bout[o];
        const float4* wr = (const float4*)(Wout + (size_t)o * (2*H));
        #pragma unroll
        for (int k = 0; k < (2*H) / 4; k++) {
            float4 w2 = wr[k]; float4 yy = yv[k];
            acc2 = fmaf(w2.x, yy.x, acc2);
            acc2 = fmaf(w2.y, yy.y, acc2);
            acc2 = fmaf(w2.z, yy.z, acc2);
            acc2 = fmaf(w2.w, yy.w, acc2);
        }
        out[(size_t)b * NC + o] = acc2;
    }
}

extern "C" void kernel_launch(void* const* d_in, const int* in_sizes, int n_in,
                              void* d_out, int out_size, void* d_ws, size_t ws_size,
                              hipStream_t stream) {
    const float* x        = (const float*)d_in[0];
    const int*   lengths  = (const int*)  d_in[1];
    const float* Wih_l0f  = (const float*)d_in[2];
    const float* Whh_l0f  = (const float*)d_in[3];
    const float* bih_l0f  = (const float*)d_in[4];
    const float* bhh_l0f  = (const float*)d_in[5];
    const float* Wih_l0b  = (const float*)d_in[6];
    const float* Whh_l0b  = (const float*)d_in[7];
    const float* bih_l0b  = (const float*)d_in[8];
    const float* bhh_l0b  = (const float*)d_in[9];
    const float* Wih_l1f  = (const float*)d_in[10];
    const float* Whh_l1f  = (const float*)d_in[11];
    const float* bih_l1f  = (const float*)d_in[12];
    const float* bhh_l1f  = (const float*)d_in[13];
    const float* Wih_l1b  = (const float*)d_in[14];
    // d_in[15] = Whh_l1b: unused (backward dir only needs its first step, h=0)
    const float* bih_l1b  = (const float*)d_in[16];
    const float* bhh_l1b  = (const float*)d_in[17];
    const float* Wout     = (const float*)d_in[18];
    const float* bout     = (const float*)d_in[19];
    float* out = (float*)d_out;

    const size_t h0_b = (size_t)BATCH * TMAX * (2*H) * sizeof(float);  // 256 MB
    const size_t st_b = (size_t)BATCH * 2 * H * sizeof(float);         // 256 KB
    float* h0    = (float*)d_ws;
    float* state = (float*)((char*)d_ws + h0_b);

    int CH = 0;
    const int cands[4] = {1024, 512, 256, 128};
    for (int i = 0; i < 4; i++) {
        const size_t need = h0_b + st_b + (size_t)cands[i] * BATCH * (4*H) * sizeof(float);
        if (ws_size >= need) { CH = cands[i]; break; }
    }

    lstm_layer0_gs<<<dim3(2 * BATCH), 128, 0, stream>>>(
        x, lengths,
        Wih_l0f, Whh_l0f, bih_l0f, bhh_l0f,
        Wih_l0b, Whh_l0b, bih_l0b, bhh_l0b, h0);

    if (CH) {
        float* G1c = (float*)((char*)d_ws + h0_b + st_b);
        for (int s0 = 0; s0 < TMAX; s0 += CH) {
            xw_gemm_chunk<<<dim3(CH / 64, BATCH), 256, 0, stream>>>(
                h0, lengths, Wih_l1f, bih_l1f, bhh_l1f, G1c, s0, CH);
            lstm_rec_gs<<<dim3(BATCH), 128, 0, stream>>>(
                G1c, h0, lengths, Whh_l1f,
                Wih_l1b, bih_l1b, bhh_l1b, Wout, bout, out, state, s0, CH);
        }
    } else {
        lstm_layer1_fused<<<dim3(BATCH), 256, 0, stream>>>(
            h0, lengths,
            Wih_l1f, Whh_l1f, bih_l1f, bhh_l1f,
            Wih_l1b, bih_l1b, bhh_l1b, Wout, bout, out);
    }
}